// Round 7
// baseline (17305.138 us; speedup 1.0000x reference)
//
#include <hip/hip_runtime.h>
#include <stdint.h>

// Problem dims
#define TT 2048
#define BB 32
#define II 256
#define HH 512
#define OO 1024
#define NWGL 16    // WGs per layer; each WG = 4 waves, owns 32 hidden units
#define NWG 32
#define RING 32    // ring slots per layer (32 KB each)
#define SLOTB (BB * HH * 2)  // 32 KB

typedef __attribute__((ext_vector_type(8))) short short8;
typedef __attribute__((ext_vector_type(4))) float floatx4;

__device__ __forceinline__ unsigned short f2bf(float f) {
  union { float f; unsigned u; } v; v.f = f;
  unsigned r = v.u + 0x7FFFu + ((v.u >> 16) & 1u);  // RNE
  return (unsigned short)(r >> 16);
}
__device__ __forceinline__ float bf2f(unsigned short b) {
  union { float f; unsigned u; } v; v.u = ((unsigned)b) << 16; return v.f;
}
__device__ __forceinline__ float sigmf(float x) { return 1.0f / (1.0f + __expf(-x)); }
__device__ __forceinline__ float tanhfast(float x) {
  float xc = fminf(fmaxf(x, -15.f), 15.f);
  float e = __expf(2.f * xc);
  return (e - 1.f) / (e + 1.f);
}

// Coherent (MALL-direct) 16B load via 64-bit VGPR address: d <- [va + IMM].
#define LD1(d, va, IMM)                                                     \
  asm volatile("global_load_dwordx4 %0, %1, off offset:" IMM " sc0 sc1"     \
               : "=v"(d) : "v"(va) : "memory")
// Cached 16B load (normal L1/L2 path) — read-only x.
#define LD1C(d, va, IMM)                                                    \
  asm volatile("global_load_dwordx4 %0, %1, off offset:" IMM                \
               : "=v"(d) : "v"(va) : "memory")

#define ISSUE8(dst, va) do {                                                \
    LD1(dst[0], va, "0");   LD1(dst[1], va, "64");                          \
    LD1(dst[2], va, "128"); LD1(dst[3], va, "192");                         \
    LD1(dst[4], va, "256"); LD1(dst[5], va, "320");                         \
    LD1(dst[6], va, "384"); LD1(dst[7], va, "448"); } while (0)
#define ISSUE4(dst, va) do {                                                \
    LD1(dst[0], va, "0");   LD1(dst[1], va, "64");                          \
    LD1(dst[2], va, "128"); LD1(dst[3], va, "192"); } while (0)
#define ISSUE2C(dst, va) do {                                               \
    LD1C(dst[0], va, "0");  LD1C(dst[1], va, "64"); } while (0)

// Wait until <=N vector-mem ops outstanding; fence the scheduler (rule #18).
#define WAITV(N) do {                                                       \
    asm volatile("s_waitcnt vmcnt(" #N ")" ::: "memory");                   \
    __builtin_amdgcn_sched_barrier(0); } while (0)

// Coherent dword load (seq words).
#define PROGREAD(dst, addr64)                                               \
  asm volatile("global_load_dword %0, %1, off sc0 sc1"                      \
               : "=v"(dst) : "v"(addr64) : "memory")

// Validate: all 16 producer words of (slot) must equal tag.
#define VALIDATE(arr, slot, tag) do {                                       \
    const unsigned long long _sa = (unsigned long long)(arr) +              \
        (unsigned long long)((slot) * 16 + (lane & 15)) * 4;                \
    int _sv; PROGREAD(_sv, _sa); WAITV(0);                                  \
    while (!__all(_sv == (tag))) {                                          \
      __builtin_amdgcn_s_sleep(1); PROGREAD(_sv, _sa); WAITV(0);            \
    } } while (0)
#define GUARDGE(arr, slot, tag) do {                                        \
    const unsigned long long _sa = (unsigned long long)(arr) +              \
        (unsigned long long)((slot) * 16 + (lane & 15)) * 4;                \
    int _sv; PROGREAD(_sv, _sa); WAITV(0);                                  \
    while (!__all(_sv >= (tag))) {                                          \
      __builtin_amdgcn_s_sleep(4); PROGREAD(_sv, _sa); WAITV(0);            \
    } } while (0)

// ---------------- x fp32 -> bf16 convert ----------------
__global__ void k_convert_x(const float* __restrict__ x, ushort* __restrict__ xb, int n4) {
  int i = blockIdx.x * blockDim.x + threadIdx.x;
  int stride = gridDim.x * blockDim.x;
  const float4* xf = reinterpret_cast<const float4*>(x);
  ushort4* ob = reinterpret_cast<ushort4*>(xb);
  for (; i < n4; i += stride) {
    float4 f = xf[i];
    ushort4 o;
    o.x = f2bf(f.x); o.y = f2bf(f.y); o.z = f2bf(f.z); o.w = f2bf(f.w);
    ob[i] = o;
  }
}

// ---------------- init: ring slot 31 = initial h, seed seq arrays ----------
__global__ void k_init(const float* __restrict__ h0in,
                       ushort* __restrict__ h0ring, ushort* __restrict__ h1ring,
                       int* __restrict__ h0seq, int* __restrict__ h1seq) {
  int i = threadIdx.x;
  ushort* s0 = h0ring + (RING - 1) * BB * HH;
  ushort* s1 = h1ring + (RING - 1) * BB * HH;
  for (int k = i; k < BB * HH; k += blockDim.x) {
    s0[k] = f2bf(h0in[k]);
    s1[k] = f2bf(h0in[BB * HH + k]);
  }
  for (int k = i; k < RING * 16; k += blockDim.x) {
    int v = (k >= (RING - 1) * 16) ? -1 : (int)0x80000000;  // slot31 tag -1
    h0seq[k] = v;
    h1seq[k] = v;
  }
}

// ---------------- persistent recurrence kernel ----------------
// 32 WGs x 4 waves. WG G of layer L owns units [32G,32G+32) = 8 col-tiles.
// Wave w takes a K-slice; partials are reduced via LDS (intra-CU), wave w
// finishes tiles {2w,2w+1} (units [32G+8w,+8)) -> nonlin -> c/h update ->
// coalesced sc0sc1 store. Each WG reads each h line ONCE (4x less coherent
// traffic than 1-wave WGs). Dataflow sync via 16-word seq arrays per slot.
__global__ __launch_bounds__(256, 1) void k_lstm(
    const ushort* __restrict__ xb,
    const float* __restrict__ w_ih0, const float* __restrict__ w_hh0,
    const float* __restrict__ b_ih0, const float* __restrict__ b_hh0,
    const float* __restrict__ w_ih1, const float* __restrict__ w_hh1,
    const float* __restrict__ b_ih1, const float* __restrict__ b_hh1,
    const float* __restrict__ c0in,
    ushort* __restrict__ h0ring, ushort* __restrict__ h1ring,
    int* __restrict__ h0seq, int* __restrict__ h1seq)
{
  // partials: plds[finisher f][source idx 0..2][dt][bt][lane]  (48 KB)
  __shared__ floatx4 plds[4][3][2][2][64];
  __shared__ ushort hsh[4][BB][8];  // per-wave 512B store-pack tiles
  const int wg = blockIdx.x;
  const int tid = threadIdx.x;
  const int w = tid >> 6;        // wave 0..3
  const int lane = tid & 63;
  const bool isL0 = wg < NWGL;
  const int G = isL0 ? wg : wg - NWGL;
  const int col = lane & 15;
  const int krow = lane >> 4;
  const int u = col & 3;
  const int gate = col >> 2;  // 0=i 1=f 2=g 3=o

  // --- bias + c-state for this wave's finish tiles (2w, 2w+1) ---
  float biasv[2];
#pragma unroll
  for (int dt = 0; dt < 2; dt++) {
    const int grow = gate * HH + G * 32 + (2 * w + dt) * 4 + u;
    biasv[dt] = isL0 ? (b_ih0[grow] + b_hh0[grow]) : (b_ih1[grow] + b_hh1[grow]);
  }
  float cst[2][2][4];
  {
    const float* cbase = c0in + (isL0 ? 0 : 1) * BB * HH;
#pragma unroll
    for (int dt = 0; dt < 2; dt++)
#pragma unroll
      for (int bt = 0; bt < 2; bt++)
#pragma unroll
        for (int r = 0; r < 4; r++) {
          int b = bt * 16 + krow * 4 + r;
          cst[dt][bt][r] = cbase[b * HH + G * 32 + (2 * w + dt) * 4 + u];
        }
  }

  const unsigned long long h0rb = (unsigned long long)h0ring;
  const unsigned long long h1rb = (unsigned long long)h1ring;
  const int vo00 = col * 1024 + krow * 16;  // [32][512]bf16 tile; bt1 = +16384
  const unsigned long long stoff =
      (unsigned long long)(lane * 1024 + (G * 4 + w) * 16);

// finish: LDS-reduce partials, nonlinearity, c/h update, store, publish
#define FINISH_PUBLISH(seqarr, ringbase, slot, tag) do {                    \
    _Pragma("unroll")                                                       \
    for (int f = 0; f < 4; f++) {                                           \
      if (f != w) {                                                         \
        int sidx = (w > f) ? (w - 1) : w;                                   \
        _Pragma("unroll")                                                   \
        for (int dt = 0; dt < 2; dt++)                                      \
          _Pragma("unroll")                                                 \
          for (int bt = 0; bt < 2; bt++)                                    \
            plds[f][sidx][dt][bt][lane] = acc[2 * f + dt][bt];              \
      }                                                                     \
    }                                                                       \
    __syncthreads();                                                        \
    floatx4 accf[2][2];                                                     \
    _Pragma("unroll")                                                       \
    for (int dt = 0; dt < 2; dt++)                                          \
      _Pragma("unroll")                                                     \
      for (int bt = 0; bt < 2; bt++) {                                      \
        floatx4 s = acc[2 * w + dt][bt];                                    \
        s = s + plds[w][0][dt][bt][lane];                                   \
        s = s + plds[w][1][dt][bt][lane];                                   \
        s = s + plds[w][2][dt][bt][lane];                                   \
        float bsc = biasv[dt];                                              \
        s[0] += bsc; s[1] += bsc; s[2] += bsc; s[3] += bsc;                 \
        accf[dt][bt] = s;                                                   \
      }                                                                     \
    _Pragma("unroll")                                                       \
    for (int dt = 0; dt < 2; dt++)                                          \
      _Pragma("unroll")                                                     \
      for (int bt = 0; bt < 2; bt++)                                        \
        _Pragma("unroll")                                                   \
        for (int r = 0; r < 4; r++) {                                       \
          float val = accf[dt][bt][r];                                      \
          float nl = (gate == 2) ? tanhfast(val) : sigmf(val);              \
          int base2 = (lane & 48) | u;                                      \
          float iv = __shfl(nl, base2);                                     \
          float fv = __shfl(nl, base2 | 4);                                 \
          float gv = __shfl(nl, base2 | 8);                                 \
          float ov = __shfl(nl, base2 | 12);                                \
          if (gate == 0) {                                                  \
            float cn = fv * cst[dt][bt][r] + iv * gv;                       \
            cst[dt][bt][r] = cn;                                            \
            float hn = ov * tanhfast(cn);                                   \
            int b = bt * 16 + krow * 4 + r;                                 \
            hsh[w][b][dt * 4 + u] = f2bf(hn);                               \
          }                                                                 \
        }                                                                   \
    asm volatile("s_waitcnt lgkmcnt(0)" ::: "memory");                      \
    __builtin_amdgcn_sched_barrier(0);                                      \
    if (lane < 32) {                                                        \
      short8 v = *reinterpret_cast<const short8*>(&hsh[w][lane][0]);        \
      unsigned long long sa = (ringbase) +                                  \
          (unsigned long long)(slot) * SLOTB + stoff;                       \
      asm volatile("global_store_dwordx4 %0, %1, off sc0 sc1"               \
                   :: "v"(sa), "v"(v) : "memory");                          \
    }                                                                       \
    WAITV(0);                                                               \
    __syncthreads();                                                        \
    if (tid == 0) {                                                         \
      unsigned long long _pa = (unsigned long long)(seqarr) +               \
          (unsigned long long)((slot) * 16 + G) * 4;                        \
      int _pv = (tag);                                                      \
      asm volatile("global_store_dword %0, %1, off sc0 sc1"                 \
                   :: "v"(_pa), "v"(_pv) : "memory");                       \
    } } while (0)

  if (isL0) {
    // ---- layer 0: K = x(256:8kf) + h0(512:16kf); wave w: x kf 2w..2w+2,
    //      h0 kf 4w..4w+4 ----
    short8 wfx[8][2], wfh[8][4];
#pragma unroll
    for (int tau = 0; tau < 8; tau++) {
      const int grow = gate * HH + G * 32 + tau * 4 + u;
#pragma unroll
      for (int j = 0; j < 2; j++) {
        const float* p = w_ih0 + (size_t)grow * II + (2 * w + j) * 32 + krow * 8;
        short8 rr;
#pragma unroll
        for (int q = 0; q < 8; q++) rr[q] = (short)f2bf(p[q]);
        wfx[tau][j] = rr;
      }
#pragma unroll
      for (int j = 0; j < 4; j++) {
        const float* p = w_hh0 + (size_t)grow * HH + (4 * w + j) * 32 + krow * 8;
        short8 rr;
#pragma unroll
        for (int q = 0; q < 8; q++) rr[q] = (short)f2bf(p[q]);
        wfh[tau][j] = rr;
      }
    }
    const unsigned long long xbase =
        (unsigned long long)xb + (col * 512 + krow * 16 + w * 128);
    for (int t = 0; t < TT; ++t) {
      VALIDATE(h0seq, (t + 31) & 31, t - 1);
      if (((t & 7) == 0) && t >= 32) GUARDGE(h1seq, (t - 24) & 31, t - 24);
      floatx4 acc[8][2];
#pragma unroll
      for (int tau = 0; tau < 8; tau++) {
        acc[tau][0] = (floatx4){0.f, 0.f, 0.f, 0.f};
        acc[tau][1] = (floatx4){0.f, 0.f, 0.f, 0.f};
      }
      const unsigned long long xa = xbase + (unsigned long long)t * (BB * II * 2);
      const unsigned long long ha =
          h0rb + (unsigned long long)((t + 31) & 31) * SLOTB + vo00 + w * 256;
      short8 sx0[2], sh0[4], sx1[2], sh1[4];
      ISSUE2C(sx0, xa); ISSUE4(sh0, ha);
      ISSUE2C(sx1, xa + 8192); ISSUE4(sh1, ha + 16384);
      WAITV(6);
#pragma unroll
      for (int tau = 0; tau < 8; tau++) {
#pragma unroll
        for (int j = 0; j < 2; j++)
          acc[tau][0] = __builtin_amdgcn_mfma_f32_16x16x32_bf16(sx0[j], wfx[tau][j], acc[tau][0], 0, 0, 0);
#pragma unroll
        for (int j = 0; j < 4; j++)
          acc[tau][0] = __builtin_amdgcn_mfma_f32_16x16x32_bf16(sh0[j], wfh[tau][j], acc[tau][0], 0, 0, 0);
      }
      WAITV(0);
#pragma unroll
      for (int tau = 0; tau < 8; tau++) {
#pragma unroll
        for (int j = 0; j < 2; j++)
          acc[tau][1] = __builtin_amdgcn_mfma_f32_16x16x32_bf16(sx1[j], wfx[tau][j], acc[tau][1], 0, 0, 0);
#pragma unroll
        for (int j = 0; j < 4; j++)
          acc[tau][1] = __builtin_amdgcn_mfma_f32_16x16x32_bf16(sh1[j], wfh[tau][j], acc[tau][1], 0, 0, 0);
      }
      FINISH_PUBLISH(h0seq, h0rb, (t & 31), t);
    }
  } else {
    // ---- layer 1: K = h0(512) + h1(512); wave 0,1 -> h0 halves,
    //      wave 2,3 -> h1 halves ----
    short8 wf[8][8];
#pragma unroll
    for (int tau = 0; tau < 8; tau++) {
      const int grow = gate * HH + G * 32 + tau * 4 + u;
      const float* wbase = (w < 2) ? w_ih1 : w_hh1;
#pragma unroll
      for (int j = 0; j < 8; j++) {
        const float* p = wbase + (size_t)grow * HH + ((w & 1) * 8 + j) * 32 + krow * 8;
        short8 rr;
#pragma unroll
        for (int q = 0; q < 8; q++) rr[q] = (short)f2bf(p[q]);
        wf[tau][j] = rr;
      }
    }
    for (int t = 0; t < TT; ++t) {
      VALIDATE(h0seq, (t & 31), t);
      VALIDATE(h1seq, (t + 31) & 31, t - 1);
      floatx4 acc[8][2];
#pragma unroll
      for (int tau = 0; tau < 8; tau++) {
        acc[tau][0] = (floatx4){0.f, 0.f, 0.f, 0.f};
        acc[tau][1] = (floatx4){0.f, 0.f, 0.f, 0.f};
      }
      const unsigned long long va =
          ((w < 2) ? (h0rb + (unsigned long long)(t & 31) * SLOTB)
                   : (h1rb + (unsigned long long)((t + 31) & 31) * SLOTB)) +
          vo00 + (w & 1) * 512;
      short8 wa[8], wb[8];
      ISSUE8(wa, va); ISSUE8(wb, va + 16384);
      WAITV(8);
#pragma unroll
      for (int tau = 0; tau < 8; tau++)
#pragma unroll
        for (int j = 0; j < 8; j++)
          acc[tau][0] = __builtin_amdgcn_mfma_f32_16x16x32_bf16(wa[j], wf[tau][j], acc[tau][0], 0, 0, 0);
      WAITV(0);
#pragma unroll
      for (int tau = 0; tau < 8; tau++)
#pragma unroll
        for (int j = 0; j < 8; j++)
          acc[tau][1] = __builtin_amdgcn_mfma_f32_16x16x32_bf16(wb[j], wf[tau][j], acc[tau][1], 0, 0, 0);
      FINISH_PUBLISH(h1seq, h1rb, (t & 31), t);
    }
  }
}

// ---------------- FC + log_softmax ----------------
__global__ __launch_bounds__(256) void k_fc(const ushort* __restrict__ h1,
                                            const float* __restrict__ fcw,
                                            const float* __restrict__ fcb,
                                            float* __restrict__ out) {
  __shared__ float hsh2[HH];
  __shared__ float red[256];
  const int b = blockIdx.x, tid = threadIdx.x;
  for (int k = tid; k < HH; k += 256) hsh2[k] = bf2f(h1[b * HH + k]);
  __syncthreads();
  float lg[4];
#pragma unroll
  for (int q = 0; q < 4; q++) {
    int o = q * 256 + tid;
    float acc = fcb[o];
    const float* wr = fcw + (size_t)o * HH;
#pragma unroll 4
    for (int k = 0; k < HH; k += 4) {
      float4 w4 = *reinterpret_cast<const float4*>(wr + k);
      acc += hsh2[k] * w4.x + hsh2[k + 1] * w4.y + hsh2[k + 2] * w4.z + hsh2[k + 3] * w4.w;
    }
    lg[q] = acc;
  }
  float m = fmaxf(fmaxf(lg[0], lg[1]), fmaxf(lg[2], lg[3]));
  red[tid] = m; __syncthreads();
  for (int s = 128; s > 0; s >>= 1) { if (tid < s) red[tid] = fmaxf(red[tid], red[tid + s]); __syncthreads(); }
  m = red[0]; __syncthreads();
  float se = 0.f;
#pragma unroll
  for (int q = 0; q < 4; q++) se += __expf(lg[q] - m);
  red[tid] = se; __syncthreads();
  for (int s = 128; s > 0; s >>= 1) { if (tid < s) red[tid] += red[tid + s]; __syncthreads(); }
  float lse = m + logf(red[0]);
#pragma unroll
  for (int q = 0; q < 4; q++) out[b * OO + q * 256 + tid] = lg[q] - lse;
}

extern "C" void kernel_launch(void* const* d_in, const int* in_sizes, int n_in,
                              void* d_out, int out_size, void* d_ws, size_t ws_size,
                              hipStream_t stream) {
  const float* x     = (const float*)d_in[0];
  const float* h0    = (const float*)d_in[1];
  const float* c0    = (const float*)d_in[2];
  const float* w_ih0 = (const float*)d_in[3];
  const float* w_hh0 = (const float*)d_in[4];
  const float* b_ih0 = (const float*)d_in[5];
  const float* b_hh0 = (const float*)d_in[6];
  const float* w_ih1 = (const float*)d_in[7];
  const float* w_hh1 = (const float*)d_in[8];
  const float* b_ih1 = (const float*)d_in[9];
  const float* b_hh1 = (const float*)d_in[10];
  const float* fcw   = (const float*)d_in[11];
  const float* fcb   = (const float*)d_in[12];
  float* out = (float*)d_out;

  char* ws = (char*)d_ws;
  size_t off = 0;
  ushort* xb     = (ushort*)(ws + off); off += (size_t)TT * BB * II * 2;     // 33.5 MB
  ushort* h0ring = (ushort*)(ws + off); off += (size_t)RING * BB * HH * 2;   // 1 MB
  ushort* h1ring = (ushort*)(ws + off); off += (size_t)RING * BB * HH * 2;   // 1 MB
  int* h0seq = (int*)(ws + off); off += RING * 16 * sizeof(int);
  int* h1seq = (int*)(ws + off); off += RING * 16 * sizeof(int);

  k_convert_x<<<2048, 256, 0, stream>>>(x, xb, TT * BB * II / 4);
  k_init<<<1, 256, 0, stream>>>(h0, h0ring, h1ring, h0seq, h1seq);
  k_lstm<<<NWG, 256, 0, stream>>>(xb, w_ih0, w_hh0, b_ih0, b_hh0,
                                  w_ih1, w_hh1, b_ih1, b_hh1, c0,
                                  h0ring, h1ring, h0seq, h1seq);
  // h1[2047] lives in ring slot 2047&31 = 31
  k_fc<<<BB, 256, 0, stream>>>(h1ring + (RING - 1) * BB * HH, fcw, fcb, out);
}